// Round 4
// baseline (262.749 us; speedup 1.0000x reference)
//
#include <hip/hip_runtime.h>
#include <math.h>

#define NN   2048
#define INF_ 256
#define OUTF 256
#define EF   64
#define ALPHA 0.2f
#define NEG_INF -9000000000000000.0f

// ---------------- prep1: w3[r] = W[r,:] . a3 ----------------
__global__ void prep1_kernel(const float* __restrict__ W, const float* __restrict__ a,
                             float* __restrict__ w3) {
    int lane = threadIdx.x & 63, wave = threadIdx.x >> 6;
    const float* a3 = a + 2 * OUTF;
    float4 av = *(const float4*)&a3[lane * 4];
    int r0 = blockIdx.x * 8 + wave * 2;
    #pragma unroll
    for (int rr = 0; rr < 2; ++rr) {
        int r = r0 + rr;
        float4 wv = *(const float4*)&W[(size_t)r * OUTF + lane * 4];
        float d = wv.x * av.x + wv.y * av.y + wv.z * av.z + wv.w * av.w;
        #pragma unroll
        for (int off = 32; off; off >>= 1) d += __shfl_xor(d, off);
        if (lane == 0) w3[r] = d;
    }
}

// ---------------- prep2: we3[r] = W_e[r,:] . w3 ----------------
__global__ void prep2_kernel(const float* __restrict__ W_e, const float* __restrict__ w3,
                             float* __restrict__ we3) {
    int lane = threadIdx.x & 63, wave = threadIdx.x >> 6;
    int r = blockIdx.x * 4 + wave;
    float4 wv = *(const float4*)&W_e[(size_t)r * INF_ + lane * 4];
    float4 xv = *(const float4*)&w3[lane * 4];
    float d = wv.x * xv.x + wv.y * xv.y + wv.z * xv.z + wv.w * xv.w;
    #pragma unroll
    for (int off = 32; off; off >>= 1) d += __shfl_xor(d, off);
    if (lane == 0) we3[r] = d;
}

// ---------------- s_src = h@a1, s_dst = h@a2 ----------------
__global__ void sv_kernel(const float* __restrict__ h, const float* __restrict__ a,
                          float* __restrict__ s_src, float* __restrict__ s_dst) {
    int lane = threadIdx.x & 63;
    int wave = threadIdx.x >> 6;
    int i = blockIdx.x * 4 + wave;
    float acc1 = 0.f, acc2 = 0.f;
    #pragma unroll
    for (int u = 0; u < 4; ++u) {
        int o = lane + u * 64;
        float hv = h[(size_t)i * OUTF + o];
        acc1 += hv * a[o];
        acc2 += hv * a[OUTF + o];
    }
    #pragma unroll
    for (int off = 32; off; off >>= 1) {
        acc1 += __shfl_xor(acc1, off);
        acc2 += __shfl_xor(acc2, off);
    }
    if (lane == 0) { s_src[i] = acc1; s_dst[i] = acc2; }
}

// ---------------- tiled f32 GEMM (h = input @ W): 64x32 tile ----------------
template<int K>
__launch_bounds__(256, 2)
__global__ void gemm_kernel(const float* __restrict__ A, const float* __restrict__ Bm,
                            float* __restrict__ C) {
    __shared__ float As[64][68];
    __shared__ float Bs[64][32];
    int tid = threadIdx.x;
    int r0 = blockIdx.x * 64;
    int c0 = blockIdx.y * 32;
    int tr = tid >> 4;
    int tc = tid & 15;
    float acc[4][2] = {};

    for (int k0 = 0; k0 < K; k0 += 64) {
        #pragma unroll
        for (int t = 0; t < 4; ++t) {
            int s = tid + t * 256;
            int row = s >> 4, col4 = s & 15;
            *(float4*)&As[row][col4 * 4] =
                *(const float4*)&A[(size_t)(r0 + row) * K + k0 + col4 * 4];
        }
        #pragma unroll
        for (int t = 0; t < 2; ++t) {
            int s = tid + t * 256;
            int row = s >> 3, col4 = s & 7;
            *(float4*)&Bs[row][col4 * 4] =
                *(const float4*)&Bm[(size_t)(k0 + row) * 256 + c0 + col4 * 4];
        }
        __syncthreads();
        #pragma unroll
        for (int kk = 0; kk < 64; kk += 4) {
            float4 aReg[4];
            float2 bReg[4];
            #pragma unroll
            for (int i = 0; i < 4; ++i) aReg[i] = *(const float4*)&As[tr * 4 + i][kk];
            #pragma unroll
            for (int q = 0; q < 4; ++q)  bReg[q] = *(const float2*)&Bs[kk + q][tc * 2];
            #pragma unroll
            for (int q = 0; q < 4; ++q) {
                float bx = bReg[q].x, by = bReg[q].y;
                #pragma unroll
                for (int i = 0; i < 4; ++i) {
                    float av = (q == 0) ? aReg[i].x : (q == 1) ? aReg[i].y
                             : (q == 2) ? aReg[i].z : aReg[i].w;
                    acc[i][0] += av * bx;
                    acc[i][1] += av * by;
                }
            }
        }
        __syncthreads();
    }
    #pragma unroll
    for (int i = 0; i < 4; ++i) {
        int r = r0 + tr * 4 + i;
        float2 v = {acc[i][0], acc[i][1]};
        *(float2*)&C[(size_t)r * 256 + c0 + tc * 2] = v;
    }
}

// ---------------- att @ h, split-K=2: grid (32, 8, 2), partial sums ----------------
__launch_bounds__(256, 2)
__global__ void gemm2_kernel(const float* __restrict__ att, const float* __restrict__ h,
                             float* __restrict__ Cpart) {
    __shared__ float As[64][68];
    __shared__ float Bs[64][32];
    int tid = threadIdx.x;
    int r0 = blockIdx.x * 64;
    int c0 = blockIdx.y * 32;
    int z  = blockIdx.z;
    int tr = tid >> 4;
    int tc = tid & 15;
    float acc[4][2] = {};

    for (int k0 = z * (NN / 2); k0 < (z + 1) * (NN / 2); k0 += 64) {
        #pragma unroll
        for (int t = 0; t < 4; ++t) {
            int s = tid + t * 256;
            int row = s >> 4, col4 = s & 15;
            *(float4*)&As[row][col4 * 4] =
                *(const float4*)&att[(size_t)(r0 + row) * NN + k0 + col4 * 4];
        }
        #pragma unroll
        for (int t = 0; t < 2; ++t) {
            int s = tid + t * 256;
            int row = s >> 3, col4 = s & 7;
            *(float4*)&Bs[row][col4 * 4] =
                *(const float4*)&h[(size_t)(k0 + row) * 256 + c0 + col4 * 4];
        }
        __syncthreads();
        #pragma unroll
        for (int kk = 0; kk < 64; kk += 4) {
            float4 aReg[4];
            float2 bReg[4];
            #pragma unroll
            for (int i = 0; i < 4; ++i) aReg[i] = *(const float4*)&As[tr * 4 + i][kk];
            #pragma unroll
            for (int q = 0; q < 4; ++q)  bReg[q] = *(const float2*)&Bs[kk + q][tc * 2];
            #pragma unroll
            for (int q = 0; q < 4; ++q) {
                float bx = bReg[q].x, by = bReg[q].y;
                #pragma unroll
                for (int i = 0; i < 4; ++i) {
                    float av = (q == 0) ? aReg[i].x : (q == 1) ? aReg[i].y
                             : (q == 2) ? aReg[i].z : aReg[i].w;
                    acc[i][0] += av * bx;
                    acc[i][1] += av * by;
                }
            }
        }
        __syncthreads();
    }
    float* Cz = Cpart + (size_t)z * NN * OUTF;
    #pragma unroll
    for (int i = 0; i < 4; ++i) {
        int r = r0 + tr * 4 + i;
        float2 v = {acc[i][0], acc[i][1]};
        *(float2*)&Cz[(size_t)r * 256 + c0 + tc * 2] = v;
    }
}

// ---------------- combine partials + normalize + ELU ----------------
__global__ void combine_kernel(const float* __restrict__ Cpart, const float* __restrict__ invs,
                               float* __restrict__ out) {
    int i = blockIdx.x, t = threadIdx.x;
    size_t idx = (size_t)i * OUTF + t;
    float v = (Cpart[idx] + Cpart[(size_t)NN * OUTF + idx]) * invs[i];
    out[idx] = v > 0.f ? v : __expf(v) - 1.f;
}

// ---------------- scores + softmax: one row per block, pipelined gated stream ----------------
__launch_bounds__(256, 4)
__global__ void score_kernel(const float* __restrict__ e_feat, const int* __restrict__ adj,
                             const float* __restrict__ s_src, const float* __restrict__ s_dst,
                             const float* __restrict__ we3,
                             float* __restrict__ att, float* __restrict__ invs) {
    __shared__ float p[NN];              // 8 KiB
    __shared__ float sdst[NN];           // 8 KiB
    __shared__ unsigned char amask[NN];  // 2 KiB
    __shared__ float swe3[EF];
    __shared__ float redm[4], reds[4];

    int tid  = threadIdx.x;
    int lane = tid & 63;
    int wave = tid >> 6;
    int i    = blockIdx.x;

    const int* arow = adj + (size_t)i * NN;
    #pragma unroll
    for (int t = 0; t < 2; ++t) {
        int s = tid * 2 + t;
        int4 a4 = ((const int4*)arow)[s];
        uchar4 m4;
        m4.x = a4.x != 0; m4.y = a4.y != 0; m4.z = a4.z != 0; m4.w = a4.w != 0;
        *(uchar4*)&amask[s * 4] = m4;
        ((float4*)sdst)[s] = ((const float4*)s_dst)[s];
    }
    if (tid < EF) swe3[tid] = we3[tid];
    __syncthreads();

    const int g  = lane >> 4;            // 4 edge-groups per wave
    const int gl = lane & 15;            // 16 lanes * float4 = 64 floats per edge
    const float4 wv = *(const float4*)&swe3[gl * 4];
    const float ssrc = s_src[i];
    const float* efrow = e_feat + (size_t)i * NN * EF;
    const int jbase = wave * (NN / 4);   // 512 cols per wave; 16 macros of 32

    // double-buffered pipeline: 8 edges/group in flight while computing previous 8
    float4 evA[8], evB[8];
    unsigned mA = 0, mB = 0;

#define ISSUE(EV, MK, m)                                                      \
    {                                                                         \
        MK = 0;                                                               \
        _Pragma("unroll")                                                     \
        for (int u = 0; u < 8; ++u) {                                         \
            int j = jbase + (m) * 32 + u * 4 + g;                             \
            int a = amask[j];                                                 \
            MK |= (unsigned)(a != 0) << u;                                    \
            if (a) EV[u] = *(const float4*)&efrow[(size_t)j * EF + gl * 4];   \
        }                                                                     \
    }

#define COMPUTE(EV, MK, m)                                                    \
    {                                                                         \
        _Pragma("unroll")                                                     \
        for (int u = 0; u < 8; ++u) {                                         \
            int j = jbase + (m) * 32 + u * 4 + g;                             \
            float sc = NEG_INF;                                               \
            if ((MK >> u) & 1) {                                              \
                float d = EV[u].x * wv.x + EV[u].y * wv.y                     \
                        + EV[u].z * wv.z + EV[u].w * wv.w;                    \
                d += __shfl_xor(d, 1);                                        \
                d += __shfl_xor(d, 2);                                        \
                d += __shfl_xor(d, 4);                                        \
                d += __shfl_xor(d, 8);                                        \
                float s = ssrc + sdst[j] + d;                                 \
                sc = (s > 0.f) ? s : ALPHA * s;                               \
            }                                                                 \
            if (gl == 0) p[j] = sc;                                           \
        }                                                                     \
    }

    ISSUE(evA, mA, 0);
    for (int m = 0; m < 16; m += 2) {
        ISSUE(evB, mB, m + 1);
        COMPUTE(evA, mA, m);
        if (m + 2 < 16) ISSUE(evA, mA, m + 2);
        COMPUTE(evB, mB, m + 1);
    }
#undef ISSUE
#undef COMPUTE
    __syncthreads();

    // block max
    float m = NEG_INF;
    for (int j = tid; j < NN; j += 256) m = fmaxf(m, p[j]);
    #pragma unroll
    for (int off = 32; off; off >>= 1) m = fmaxf(m, __shfl_xor(m, off));
    if (lane == 0) redm[wave] = m;
    __syncthreads();
    m = fmaxf(fmaxf(redm[0], redm[1]), fmaxf(redm[2], redm[3]));

    // exp + write unnormalized + sum
    float* arowo = att + (size_t)i * NN;
    float sum = 0.f;
    for (int j = tid; j < NN; j += 256) {
        float e = __expf(p[j] - m);
        arowo[j] = e;
        sum += e;
    }
    #pragma unroll
    for (int off = 32; off; off >>= 1) sum += __shfl_xor(sum, off);
    if (lane == 0) reds[wave] = sum;
    __syncthreads();
    if (tid == 0) invs[i] = 1.f / (reds[0] + reds[1] + reds[2] + reds[3]);
}

extern "C" void kernel_launch(void* const* d_in, const int* in_sizes, int n_in,
                              void* d_out, int out_size, void* d_ws, size_t ws_size,
                              hipStream_t stream) {
    const float* input  = (const float*)d_in[0];
    const int*   adj    = (const int*)  d_in[1];
    const float* e_feat = (const float*)d_in[2];
    const float* W_e    = (const float*)d_in[3];
    const float* W      = (const float*)d_in[4];
    const float* a      = (const float*)d_in[5];
    float* out = (float*)d_out;

    float* h     = (float*)d_ws;                  // 2048*256
    float* s_src = h + (size_t)NN * OUTF;         // 2048
    float* s_dst = s_src + NN;                    // 2048
    float* we3   = s_dst + NN;                    // 64
    float* w3    = we3 + EF;                      // 256
    float* invs  = w3 + INF_;                     // 2048
    float* att   = invs + NN;                     // 2048*2048
    float* cpart = att + (size_t)NN * NN;         // 2 * 2048*256

    prep1_kernel<<<32, 256, 0, stream>>>(W, a, w3);
    prep2_kernel<<<16, 256, 0, stream>>>(W_e, w3, we3);
    gemm_kernel<INF_><<<dim3(NN / 64, 8), 256, 0, stream>>>(input, W, h);
    sv_kernel<<<NN / 4, 256, 0, stream>>>(h, a, s_src, s_dst);
    score_kernel<<<NN, 256, 0, stream>>>(e_feat, adj, s_src, s_dst, we3, att, invs);
    gemm2_kernel<<<dim3(NN / 64, 8, 2), 256, 0, stream>>>(att, h, cpart);
    combine_kernel<<<NN, 256, 0, stream>>>(cpart, invs, out);
}

// Round 5
// 187.484 us; speedup vs baseline: 1.4014x; 1.4014x over previous
//
#include <hip/hip_runtime.h>
#include <math.h>

#define NN   2048
#define INF_ 256
#define OUTF 256
#define EF   64
#define ALPHA 0.2f
#define NEG_INF -9000000000000000.0f

typedef unsigned short ushortT;

__device__ __forceinline__ float b2f(ushortT u) {
    unsigned v = (unsigned)u << 16;
    return *(float*)&v;
}
__device__ __forceinline__ ushortT f2b(float f) {      // RNE; inputs are finite
    unsigned b = *(unsigned*)&f;
    unsigned r = (b + 0x7FFFu + ((b >> 16) & 1u)) >> 16;
    return (ushortT)r;
}

// ---------------- prep1: w3[r] = W[r,:] . a3 ----------------
__global__ void prep1_kernel(const float* __restrict__ W, const float* __restrict__ a,
                             float* __restrict__ w3) {
    int lane = threadIdx.x & 63, wave = threadIdx.x >> 6;
    const float* a3 = a + 2 * OUTF;
    float4 av = *(const float4*)&a3[lane * 4];
    int r0 = blockIdx.x * 8 + wave * 2;
    #pragma unroll
    for (int rr = 0; rr < 2; ++rr) {
        int r = r0 + rr;
        float4 wv = *(const float4*)&W[(size_t)r * OUTF + lane * 4];
        float d = wv.x * av.x + wv.y * av.y + wv.z * av.z + wv.w * av.w;
        #pragma unroll
        for (int off = 32; off; off >>= 1) d += __shfl_xor(d, off);
        if (lane == 0) w3[r] = d;
    }
}

// ---------------- prep2: we3[r] = W_e[r,:] . w3 ----------------
__global__ void prep2_kernel(const float* __restrict__ W_e, const float* __restrict__ w3,
                             float* __restrict__ we3) {
    int lane = threadIdx.x & 63, wave = threadIdx.x >> 6;
    int r = blockIdx.x * 4 + wave;
    float4 wv = *(const float4*)&W_e[(size_t)r * INF_ + lane * 4];
    float4 xv = *(const float4*)&w3[lane * 4];
    float d = wv.x * xv.x + wv.y * xv.y + wv.z * xv.z + wv.w * xv.w;
    #pragma unroll
    for (int off = 32; off; off >>= 1) d += __shfl_xor(d, off);
    if (lane == 0) we3[r] = d;
}

// ---------------- s_src = h@a1, s_dst = h@a2 ----------------
__global__ void sv_kernel(const float* __restrict__ h, const float* __restrict__ a,
                          float* __restrict__ s_src, float* __restrict__ s_dst) {
    int lane = threadIdx.x & 63;
    int wave = threadIdx.x >> 6;
    int i = blockIdx.x * 4 + wave;
    float acc1 = 0.f, acc2 = 0.f;
    #pragma unroll
    for (int u = 0; u < 4; ++u) {
        int o = lane + u * 64;
        float hv = h[(size_t)i * OUTF + o];
        acc1 += hv * a[o];
        acc2 += hv * a[OUTF + o];
    }
    #pragma unroll
    for (int off = 32; off; off >>= 1) {
        acc1 += __shfl_xor(acc1, off);
        acc2 += __shfl_xor(acc2, off);
    }
    if (lane == 0) { s_src[i] = acc1; s_dst[i] = acc2; }
}

// ---------------- h = input @ W: 64x32 tile f32 ----------------
template<int K>
__launch_bounds__(256, 2)
__global__ void gemm_kernel(const float* __restrict__ A, const float* __restrict__ Bm,
                            float* __restrict__ C) {
    __shared__ float As[64][68];
    __shared__ float Bs[64][32];
    int tid = threadIdx.x;
    int r0 = blockIdx.x * 64;
    int c0 = blockIdx.y * 32;
    int tr = tid >> 4;
    int tc = tid & 15;
    float acc[4][2] = {};

    for (int k0 = 0; k0 < K; k0 += 64) {
        #pragma unroll
        for (int t = 0; t < 4; ++t) {
            int s = tid + t * 256;
            int row = s >> 4, col4 = s & 15;
            *(float4*)&As[row][col4 * 4] =
                *(const float4*)&A[(size_t)(r0 + row) * K + k0 + col4 * 4];
        }
        #pragma unroll
        for (int t = 0; t < 2; ++t) {
            int s = tid + t * 256;
            int row = s >> 3, col4 = s & 7;
            *(float4*)&Bs[row][col4 * 4] =
                *(const float4*)&Bm[(size_t)(k0 + row) * 256 + c0 + col4 * 4];
        }
        __syncthreads();
        #pragma unroll
        for (int kk = 0; kk < 64; kk += 4) {
            float4 aReg[4];
            float2 bReg[4];
            #pragma unroll
            for (int i = 0; i < 4; ++i) aReg[i] = *(const float4*)&As[tr * 4 + i][kk];
            #pragma unroll
            for (int q = 0; q < 4; ++q)  bReg[q] = *(const float2*)&Bs[kk + q][tc * 2];
            #pragma unroll
            for (int q = 0; q < 4; ++q) {
                float bx = bReg[q].x, by = bReg[q].y;
                #pragma unroll
                for (int i = 0; i < 4; ++i) {
                    float av = (q == 0) ? aReg[i].x : (q == 1) ? aReg[i].y
                             : (q == 2) ? aReg[i].z : aReg[i].w;
                    acc[i][0] += av * bx;
                    acc[i][1] += av * by;
                }
            }
        }
        __syncthreads();
    }
    #pragma unroll
    for (int i = 0; i < 4; ++i) {
        int r = r0 + tr * 4 + i;
        float2 v = {acc[i][0], acc[i][1]};
        *(float2*)&C[(size_t)r * 256 + c0 + tc * 2] = v;
    }
}

// ---------------- att(bf16) @ h: 64x64 tile, split-K=4, grid (32,4,4) ----------------
__launch_bounds__(256, 2)
__global__ void gemm2_kernel(const ushortT* __restrict__ attb, const float* __restrict__ h,
                             float* __restrict__ Cpart) {
    __shared__ float As[64][68];
    __shared__ float Bs[64][68];
    int tid = threadIdx.x;
    int r0 = blockIdx.x * 64;
    int c0 = blockIdx.y * 64;
    int z  = blockIdx.z;
    int tr = tid >> 4;                   // 4 rows each
    int tc = tid & 15;                   // 4 cols each
    float acc[4][4] = {};

    for (int k0 = z * (NN / 4); k0 < (z + 1) * (NN / 4); k0 += 64) {
        #pragma unroll
        for (int t = 0; t < 4; ++t) {    // stage A: 64x64 bf16 -> f32
            int s = tid + t * 256;
            int row = s >> 4, col4 = s & 15;
            ushort4 v = *(const ushort4*)&attb[(size_t)(r0 + row) * NN + k0 + col4 * 4];
            As[row][col4 * 4 + 0] = b2f(v.x);
            As[row][col4 * 4 + 1] = b2f(v.y);
            As[row][col4 * 4 + 2] = b2f(v.z);
            As[row][col4 * 4 + 3] = b2f(v.w);
        }
        #pragma unroll
        for (int t = 0; t < 4; ++t) {    // stage B: 64x64 f32
            int s = tid + t * 256;
            int row = s >> 4, col4 = s & 15;
            *(float4*)&Bs[row][col4 * 4] =
                *(const float4*)&h[(size_t)(k0 + row) * 256 + c0 + col4 * 4];
        }
        __syncthreads();
        #pragma unroll
        for (int kk = 0; kk < 64; kk += 4) {
            float4 aReg[4];
            float4 bReg[4];
            #pragma unroll
            for (int i = 0; i < 4; ++i) aReg[i] = *(const float4*)&As[tr * 4 + i][kk];
            #pragma unroll
            for (int q = 0; q < 4; ++q)  bReg[q] = *(const float4*)&Bs[kk + q][tc * 4];
            #pragma unroll
            for (int q = 0; q < 4; ++q) {
                #pragma unroll
                for (int i = 0; i < 4; ++i) {
                    float av = (q == 0) ? aReg[i].x : (q == 1) ? aReg[i].y
                             : (q == 2) ? aReg[i].z : aReg[i].w;
                    acc[i][0] += av * bReg[q].x;
                    acc[i][1] += av * bReg[q].y;
                    acc[i][2] += av * bReg[q].z;
                    acc[i][3] += av * bReg[q].w;
                }
            }
        }
        __syncthreads();
    }
    float* Cz = Cpart + (size_t)z * NN * OUTF;
    #pragma unroll
    for (int i = 0; i < 4; ++i) {
        int r = r0 + tr * 4 + i;
        float4 v = {acc[i][0], acc[i][1], acc[i][2], acc[i][3]};
        *(float4*)&Cz[(size_t)r * 256 + c0 + tc * 4] = v;
    }
}

// ---------------- combine 4 partials + normalize + ELU ----------------
__global__ void combine_kernel(const float* __restrict__ Cpart, const float* __restrict__ invs,
                               float* __restrict__ out) {
    int i = blockIdx.x, t = threadIdx.x;
    size_t idx = (size_t)i * OUTF + t;
    const size_t P = (size_t)NN * OUTF;
    float v = (Cpart[idx] + Cpart[P + idx] + Cpart[2 * P + idx] + Cpart[3 * P + idx]) * invs[i];
    out[idx] = v > 0.f ? v : __expf(v) - 1.f;
}

// ---------------- scores + softmax (R3 structure), bf16 att output ----------------
__launch_bounds__(256, 8)
__global__ void score_kernel(const float* __restrict__ e_feat, const int* __restrict__ adj,
                             const float* __restrict__ s_src, const float* __restrict__ s_dst,
                             const float* __restrict__ we3,
                             ushortT* __restrict__ attb, float* __restrict__ invs) {
    __shared__ float p[NN];              // 8 KiB
    __shared__ float sdst[NN];           // 8 KiB
    __shared__ unsigned char amask[NN];  // 2 KiB
    __shared__ float swe3[EF];
    __shared__ float redm[4], reds[4];

    int tid  = threadIdx.x;
    int lane = tid & 63;
    int wave = tid >> 6;
    int i    = blockIdx.x;

    const int* arow = adj + (size_t)i * NN;
    #pragma unroll
    for (int t = 0; t < 2; ++t) {
        int s = tid * 2 + t;
        int4 a4 = ((const int4*)arow)[s];
        uchar4 m4;
        m4.x = a4.x != 0; m4.y = a4.y != 0; m4.z = a4.z != 0; m4.w = a4.w != 0;
        *(uchar4*)&amask[s * 4] = m4;
        ((float4*)sdst)[s] = ((const float4*)s_dst)[s];
    }
    if (tid < EF) swe3[tid] = we3[tid];
    __syncthreads();

    const int g  = lane >> 4;            // 4 edge-groups per wave
    const int gl = lane & 15;            // 16 lanes * float4 = 64 floats per edge
    const float4 wv = *(const float4*)&swe3[gl * 4];
    const float ssrc = s_src[i];
    const float* efrow = e_feat + (size_t)i * NN * EF;

    const int jbase = wave * (NN / 4);
    for (int j0 = 0; j0 < NN / 4; j0 += 16) {    // 4 edges in flight per group
        int    av[4];
        float4 ev[4];
        #pragma unroll
        for (int u = 0; u < 4; ++u) {
            int j = jbase + j0 + u * 4 + g;
            av[u] = amask[j];
            if (av[u] != 0)
                ev[u] = *(const float4*)&efrow[(size_t)j * EF + gl * 4];
        }
        #pragma unroll
        for (int u = 0; u < 4; ++u) {
            int j = jbase + j0 + u * 4 + g;
            float sc = NEG_INF;
            if (av[u] != 0) {
                float d = ev[u].x * wv.x + ev[u].y * wv.y + ev[u].z * wv.z + ev[u].w * wv.w;
                d += __shfl_xor(d, 1);
                d += __shfl_xor(d, 2);
                d += __shfl_xor(d, 4);
                d += __shfl_xor(d, 8);
                float s = ssrc + sdst[j] + d;
                sc = (s > 0.f) ? s : ALPHA * s;
            }
            if (gl == 0) p[j] = sc;
        }
    }
    __syncthreads();

    // block max
    float m = NEG_INF;
    for (int j = tid; j < NN; j += 256) m = fmaxf(m, p[j]);
    #pragma unroll
    for (int off = 32; off; off >>= 1) m = fmaxf(m, __shfl_xor(m, off));
    if (lane == 0) redm[wave] = m;
    __syncthreads();
    m = fmaxf(fmaxf(redm[0], redm[1]), fmaxf(redm[2], redm[3]));

    // exp + write unnormalized bf16 + sum
    ushortT* arowo = attb + (size_t)i * NN;
    float sum = 0.f;
    for (int j = tid * 2; j < NN; j += 512) {
        float e0 = __expf(p[j]     - m);
        float e1 = __expf(p[j + 1] - m);
        ushort2 uu; uu.x = f2b(e0); uu.y = f2b(e1);
        *(ushort2*)&arowo[j] = uu;
        sum += e0 + e1;
    }
    #pragma unroll
    for (int off = 32; off; off >>= 1) sum += __shfl_xor(sum, off);
    if (lane == 0) reds[wave] = sum;
    __syncthreads();
    if (tid == 0) invs[i] = 1.f / (reds[0] + reds[1] + reds[2] + reds[3]);
}

extern "C" void kernel_launch(void* const* d_in, const int* in_sizes, int n_in,
                              void* d_out, int out_size, void* d_ws, size_t ws_size,
                              hipStream_t stream) {
    const float* input  = (const float*)d_in[0];
    const int*   adj    = (const int*)  d_in[1];
    const float* e_feat = (const float*)d_in[2];
    const float* W_e    = (const float*)d_in[3];
    const float* W      = (const float*)d_in[4];
    const float* a      = (const float*)d_in[5];
    float* out = (float*)d_out;

    float*   ws    = (float*)d_ws;
    float*   h     = ws;                          // 524288 floats (2 MB)
    float*   s_src = h + (size_t)NN * OUTF;       // 2048
    float*   s_dst = s_src + NN;                  // 2048
    float*   w3    = s_dst + NN;                  // 256
    float*   we3   = w3 + INF_;                   // 64
    float*   invs  = we3 + EF;                    // 2048
    ushortT* attb  = (ushortT*)(invs + NN);       // 2048*2048 bf16 (8.4 MB)
    float*   cpart = (float*)(attb + (size_t)NN * NN);  // 4 * 2048*256 f32 (8.4 MB)

    prep1_kernel<<<32, 256, 0, stream>>>(W, a, w3);
    prep2_kernel<<<16, 256, 0, stream>>>(W_e, w3, we3);
    gemm_kernel<INF_><<<dim3(NN / 64, 8), 256, 0, stream>>>(input, W, h);
    sv_kernel<<<NN / 4, 256, 0, stream>>>(h, a, s_src, s_dst);
    score_kernel<<<NN, 256, 0, stream>>>(e_feat, adj, s_src, s_dst, we3, attb, invs);
    gemm2_kernel<<<dim3(NN / 64, 4, 4), 256, 0, stream>>>(attb, h, cpart);
    combine_kernel<<<NN, 256, 0, stream>>>(cpart, invs, out);
}